// Round 3
// baseline (9313.709 us; speedup 1.0000x reference)
//
#include <hip/hip_runtime.h>

#define NP 131072
#define D 128
#define KC 2048
#define ITERS 5

#define BM 128
#define BN 128
#define ROWF4 9        // LDS row stride in float4 (32 floats + pad)
#define TAU 0.008f     // f32 top-2 gap below which we recheck in f64

// ---------------------------------------------------------------------------
// init: C64/C32/CT64 from init centroids
// ---------------------------------------------------------------------------
__global__ void init_kernel(const float* __restrict__ initC,
                            double* __restrict__ C64, float* __restrict__ C32,
                            double* __restrict__ CT64) {
    int t = blockIdx.x * 256 + threadIdx.x;       // 262144
    float v = initC[t];
    C64[t] = (double)v;
    C32[t] = v;
    CT64[(size_t)(t & 127) * KC + (t >> 7)] = (double)v;
}

// ---------------------------------------------------------------------------
// wave-per-row norms, f64 accumulate (exact products), write f64 + f32
// ---------------------------------------------------------------------------
__global__ void xnorm_kernel(const float* __restrict__ A,
                             double* __restrict__ n64, float* __restrict__ n32) {
    int r = blockIdx.x * 4 + (threadIdx.x >> 6);
    int lane = threadIdx.x & 63;
    float2 v = *(const float2*)&A[(size_t)r * D + lane * 2];
    double s = (double)v.x * (double)v.x + (double)v.y * (double)v.y;
#pragma unroll
    for (int m = 1; m < 64; m <<= 1) s += __shfl_xor(s, m, 64);
    if (lane == 0) { n64[r] = s; n32[r] = (float)s; }
}

__global__ void cnorm_kernel(const double* __restrict__ C64,
                             double* __restrict__ n64, float* __restrict__ n32,
                             int* __restrict__ counter) {
    int r = blockIdx.x * 4 + (threadIdx.x >> 6);
    int lane = threadIdx.x & 63;
    double a = C64[(size_t)r * D + lane * 2];
    double b = C64[(size_t)r * D + lane * 2 + 1];
    double s = a * a + b * b;
#pragma unroll
    for (int m = 1; m < 64; m <<= 1) s += __shfl_xor(s, m, 64);
    if (lane == 0) { n64[r] = s; n32[r] = (float)s; }
    if (blockIdx.x == 0 && threadIdx.x == 0) *counter = 0;
}

// ---------------------------------------------------------------------------
// Fast f32 GEMM + top-2 argmax. 128x128 tile, 256 thr, 8x8 micro-tile.
// Points with top-2 gap < TAU get appended to the recheck list.
// ---------------------------------------------------------------------------
__global__ void assign_kernel(const float* __restrict__ X,
                              const float* __restrict__ C,
                              const float* __restrict__ xnorm,
                              const float* __restrict__ cnorm,
                              int* __restrict__ labels,
                              int* __restrict__ list,
                              int* __restrict__ counter) {
    __shared__ float4 As[BM * ROWF4];
    __shared__ float4 Bs[BN * ROWF4];

    const int tid = threadIdx.x;
    const int tx = tid & 15;        // cluster direction
    const int ty = tid >> 4;        // point direction
    const int pbase = blockIdx.x * BM;

    float xn[8];
#pragma unroll
    for (int i = 0; i < 8; i++) xn[i] = xnorm[pbase + ty + 16 * i];

    float b1[8], b2[8];
    int i1[8];
#pragma unroll
    for (int i = 0; i < 8; i++) { b1[i] = -INFINITY; b2[i] = -INFINITY; i1[i] = 0x7fffffff; }

    for (int ct = 0; ct < KC / BN; ct++) {
        float cnj[8];
#pragma unroll
        for (int j = 0; j < 8; j++) cnj[j] = cnorm[ct * BN + tx + 16 * j];

        float acc[8][8];
#pragma unroll
        for (int i = 0; i < 8; i++)
#pragma unroll
            for (int j = 0; j < 8; j++) acc[i][j] = 0.0f;

        for (int dc = 0; dc < D; dc += 32) {
            __syncthreads();
#pragma unroll
            for (int s = 0; s < 4; s++) {
                int q = tid + 256 * s;
                int row = q >> 3, c4 = q & 7;
                As[row * ROWF4 + c4] = *(const float4*)&X[(size_t)(pbase + row) * D + dc + c4 * 4];
                Bs[row * ROWF4 + c4] = *(const float4*)&C[(size_t)(ct * BN + row) * D + dc + c4 * 4];
            }
            __syncthreads();
#pragma unroll
            for (int d4 = 0; d4 < 8; d4++) {
                float4 av[8], bv[8];
#pragma unroll
                for (int i = 0; i < 8; i++) av[i] = As[(ty + 16 * i) * ROWF4 + d4];
#pragma unroll
                for (int j = 0; j < 8; j++) bv[j] = Bs[(tx + 16 * j) * ROWF4 + d4];
#pragma unroll
                for (int i = 0; i < 8; i++)
#pragma unroll
                    for (int j = 0; j < 8; j++) {
                        float a = acc[i][j];
                        a = __builtin_fmaf(av[i].x, bv[j].x, a);
                        a = __builtin_fmaf(av[i].y, bv[j].y, a);
                        a = __builtin_fmaf(av[i].z, bv[j].z, a);
                        a = __builtin_fmaf(av[i].w, bv[j].w, a);
                        acc[i][j] = a;
                    }
            }
        }

        // epilogue: s = (2*dot - xn) - cn; running top-2 (ascending c order)
#pragma unroll
        for (int i = 0; i < 8; i++)
#pragma unroll
            for (int j = 0; j < 8; j++) {
                int c = ct * BN + tx + 16 * j;
                float s2 = __fsub_rn(__fsub_rn(__fadd_rn(acc[i][j], acc[i][j]), xn[i]), cnj[j]);
                if (s2 > b1[i]) { b2[i] = b1[i]; b1[i] = s2; i1[i] = c; }
                else if (s2 > b2[i]) b2[i] = s2;
            }
    }

    // merge top-2 across the 16 tx lanes of each row group
#pragma unroll
    for (int i = 0; i < 8; i++) {
#pragma unroll
        for (int m = 1; m < 16; m <<= 1) {
            float ob1 = __shfl_xor(b1[i], m, 64);
            int   oi  = __shfl_xor(i1[i], m, 64);
            float ob2 = __shfl_xor(b2[i], m, 64);
            if (ob1 > b1[i])      { b2[i] = fmaxf(b1[i], ob2); b1[i] = ob1; i1[i] = oi; }
            else if (ob1 < b1[i]) { b2[i] = fmaxf(b2[i], ob1); }
            else                  { b2[i] = b1[i]; i1[i] = (oi < i1[i]) ? oi : i1[i]; }
        }
    }

    if (tx == 0) {
#pragma unroll
        for (int i = 0; i < 8; i++) {
            int p = pbase + ty + 16 * i;
            labels[p] = i1[i];
            if (b1[i] - b2[i] < TAU) {
                int idx = atomicAdd(counter, 1);
                list[idx] = p;
            }
        }
    }
}

// ---------------------------------------------------------------------------
// f64 recheck of flagged points: exact argmax over all 2048 clusters.
// CT64 is [d][k] so lanes read consecutive clusters (coalesced).
// ---------------------------------------------------------------------------
__global__ void recheck_kernel(const float* __restrict__ X,
                               const double* __restrict__ CT64,
                               const double* __restrict__ xn64,
                               const double* __restrict__ cn64,
                               const int* __restrict__ list,
                               const int* __restrict__ counter,
                               int* __restrict__ labels) {
    __shared__ float xrow[D];
    __shared__ double rb[4];
    __shared__ int ri[4];
    int cnt = *counter;
    for (int ii = blockIdx.x; ii < cnt; ii += gridDim.x) {
        int p = list[ii];
        __syncthreads();
        if (threadIdx.x < D) xrow[threadIdx.x] = X[(size_t)p * D + threadIdx.x];
        __syncthreads();
        double best = -1.0e300;
        int bi = 0x7fffffff;
#pragma unroll
        for (int g = 0; g < 8; g++) {
            int c = threadIdx.x + 256 * g;
            double acc = 0.0;
#pragma unroll 16
            for (int d = 0; d < D; d++)
                acc = fma((double)xrow[d], CT64[(size_t)d * KC + c], acc);
            double s = 2.0 * acc - xn64[p] - cn64[c];
            if (s > best || (s == best && c < bi)) { best = s; bi = c; }
        }
#pragma unroll
        for (int m = 1; m < 64; m <<= 1) {
            double ob = __shfl_xor(best, m, 64);
            int oi = __shfl_xor(bi, m, 64);
            if (ob > best || (ob == best && oi < bi)) { best = ob; bi = oi; }
        }
        int w = threadIdx.x >> 6;
        if ((threadIdx.x & 63) == 0) { rb[w] = best; ri[w] = bi; }
        __syncthreads();
        if (threadIdx.x == 0) {
            double bb = rb[0]; int bbi = ri[0];
            for (int w2 = 1; w2 < 4; w2++)
                if (rb[w2] > bb || (rb[w2] == bb && ri[w2] < bbi)) { bb = rb[w2]; bbi = ri[w2]; }
            labels[p] = bbi;
        }
    }
}

// ---------------------------------------------------------------------------
// Deterministic f64 segment sums: wave per cluster, ballot-gather ascending.
// ---------------------------------------------------------------------------
__global__ void accum_kernel(const float* __restrict__ X,
                             const int* __restrict__ labels,
                             double* __restrict__ sums,
                             int* __restrict__ counts) {
    int k = blockIdx.x * 4 + (threadIdx.x >> 6);
    int lane = threadIdx.x & 63;
    double s0 = 0.0, s1 = 0.0;
    int cnt = 0;
    for (int base = 0; base < NP; base += 64) {
        int lab = labels[base + lane];
        unsigned long long m = __ballot(lab == k);
        cnt += __popcll(m);
        while (m) {
            int b = __ffsll(m) - 1;
            m &= m - 1;
            float2 v = *(const float2*)&X[(size_t)(base + b) * D + lane * 2];
            s0 += (double)v.x;
            s1 += (double)v.y;
        }
    }
    sums[(size_t)k * D + lane * 2]     = s0;
    sums[(size_t)k * D + lane * 2 + 1] = s1;
    if (lane == 0) counts[k] = cnt;
}

// ---------------------------------------------------------------------------
// update: C = count>0 ? sum/count : 0 (f64), mirror to f32 + transposed f64
// ---------------------------------------------------------------------------
__global__ void update_kernel(const double* __restrict__ sums,
                              const int* __restrict__ counts,
                              double* __restrict__ C64, float* __restrict__ C32,
                              double* __restrict__ CT64, float* __restrict__ outC) {
    int t = blockIdx.x * 256 + threadIdx.x;       // 262144
    int k = t >> 7;
    int n = counts[k];
    double v = (n > 0) ? sums[t] / (double)n : 0.0;
    C64[t] = v;
    C32[t] = (float)v;
    CT64[(size_t)(t & 127) * KC + k] = v;
    if (outC) outC[t] = (float)v;
}

__global__ void lab2f_kernel(const int* __restrict__ labels, float* __restrict__ out) {
    int t = blockIdx.x * 256 + threadIdx.x;
    out[t] = (float)labels[t];
}

extern "C" void kernel_launch(void* const* d_in, const int* in_sizes, int n_in,
                              void* d_out, int out_size, void* d_ws, size_t ws_size,
                              hipStream_t stream) {
    const float* X = (const float*)d_in[0];
    const float* initC = (const float*)d_in[1];
    float* out = (float*)d_out;

    char* w = (char*)d_ws;
    double* C64    = (double*)(w);                     // 2 MB
    double* S64    = (double*)(w + (2u << 20));        // 2 MB
    double* CT64   = (double*)(w + (4u << 20));        // 2 MB
    double* xn64   = (double*)(w + (6u << 20));        // 1 MB
    double* cn64   = (double*)(w + (7u << 20));        // 16 KB
    float*  C32    = (float*) (w + (7u << 20) + (64u << 10));   // 1 MB
    float*  xn32   = (float*) (w + (8u << 20) + (64u << 10));   // 512 KB
    float*  cn32   = (float*) (w + (8u << 20) + (576u << 10));  // 8 KB
    int*    labels = (int*)   (w + (8u << 20) + (640u << 10));  // 512 KB
    int*    list   = (int*)   (w + (9u << 20) + (128u << 10));  // 512 KB
    int*    counts = (int*)   (w + (9u << 20) + (640u << 10));  // 8 KB
    int*    counter= (int*)   (w + (9u << 20) + (656u << 10));  // 4 B

    init_kernel<<<(KC * D) / 256, 256, 0, stream>>>(initC, C64, C32, CT64);
    xnorm_kernel<<<NP / 4, 256, 0, stream>>>(X, xn64, xn32);

    for (int it = 0; it < ITERS; it++) {
        cnorm_kernel<<<KC / 4, 256, 0, stream>>>(C64, cn64, cn32, counter);
        assign_kernel<<<NP / BM, 256, 0, stream>>>(X, C32, xn32, cn32, labels, list, counter);
        recheck_kernel<<<1024, 256, 0, stream>>>(X, CT64, xn64, cn64, list, counter, labels);
        accum_kernel<<<KC / 4, 256, 0, stream>>>(X, labels, S64, counts);
        update_kernel<<<(KC * D) / 256, 256, 0, stream>>>(
            S64, counts, C64, C32, CT64, (it == ITERS - 1) ? out : nullptr);
    }
    lab2f_kernel<<<NP / 256, 256, 0, stream>>>(labels, out + (size_t)KC * D);
}

// Round 4
// 8283.317 us; speedup vs baseline: 1.1244x; 1.1244x over previous
//
#include <hip/hip_runtime.h>

#define NP 131072
#define D 128
#define KC 2048
#define ITERS 5

#define BM 128
#define BN 128
#define ROWF4 9        // LDS row stride in float4 (32 floats + pad)
#define TAU 0.008f     // f32 top-2 gap below which we recheck in f64

// ---------------------------------------------------------------------------
// init: C64/C32/CT64 from init centroids
// ---------------------------------------------------------------------------
__global__ void init_kernel(const float* __restrict__ initC,
                            double* __restrict__ C64, float* __restrict__ C32,
                            double* __restrict__ CT64) {
    int t = blockIdx.x * 256 + threadIdx.x;       // 262144
    float v = initC[t];
    C64[t] = (double)v;
    C32[t] = v;
    CT64[(size_t)(t & 127) * KC + (t >> 7)] = (double)v;
}

// ---------------------------------------------------------------------------
// wave-per-row norms, f64 accumulate (exact products), write f64 + f32
// ---------------------------------------------------------------------------
__global__ void xnorm_kernel(const float* __restrict__ A,
                             double* __restrict__ n64, float* __restrict__ n32) {
    int r = blockIdx.x * 4 + (threadIdx.x >> 6);
    int lane = threadIdx.x & 63;
    float2 v = *(const float2*)&A[(size_t)r * D + lane * 2];
    double s = (double)v.x * (double)v.x + (double)v.y * (double)v.y;
#pragma unroll
    for (int m = 1; m < 64; m <<= 1) s += __shfl_xor(s, m, 64);
    if (lane == 0) { n64[r] = s; n32[r] = (float)s; }
}

__global__ void cnorm_kernel(const double* __restrict__ C64,
                             double* __restrict__ n64, float* __restrict__ n32,
                             int* __restrict__ counter) {
    int r = blockIdx.x * 4 + (threadIdx.x >> 6);
    int lane = threadIdx.x & 63;
    double a = C64[(size_t)r * D + lane * 2];
    double b = C64[(size_t)r * D + lane * 2 + 1];
    double s = a * a + b * b;
#pragma unroll
    for (int m = 1; m < 64; m <<= 1) s += __shfl_xor(s, m, 64);
    if (lane == 0) { n64[r] = s; n32[r] = (float)s; }
    if (blockIdx.x == 0 && threadIdx.x == 0) *counter = 0;
}

// ---------------------------------------------------------------------------
// Fast f32 GEMM + top-2 argmax. 128x128 tile, 256 thr, 8x8 micro-tile.
// __launch_bounds__(256,2): cap 256 VGPR so the ~190 live values don't spill
// (default 1024-thread bound capped us at 64 VGPR -> 2.7 GB/dispatch scratch
// traffic in R3's counters).
// Points with top-2 gap < TAU get appended to the recheck list.
// ---------------------------------------------------------------------------
__global__ __launch_bounds__(256, 2)
void assign_kernel(const float* __restrict__ X,
                   const float* __restrict__ C,
                   const float* __restrict__ xnorm,
                   const float* __restrict__ cnorm,
                   int* __restrict__ labels,
                   int* __restrict__ list,
                   int* __restrict__ counter) {
    __shared__ float4 As[BM * ROWF4];
    __shared__ float4 Bs[BN * ROWF4];

    const int tid = threadIdx.x;
    const int tx = tid & 15;        // cluster direction
    const int ty = tid >> 4;        // point direction
    const int pbase = blockIdx.x * BM;

    float xn[8];
#pragma unroll
    for (int i = 0; i < 8; i++) xn[i] = xnorm[pbase + ty + 16 * i];

    float b1[8], b2[8];
    int i1[8];
#pragma unroll
    for (int i = 0; i < 8; i++) { b1[i] = -INFINITY; b2[i] = -INFINITY; i1[i] = 0x7fffffff; }

    for (int ct = 0; ct < KC / BN; ct++) {
        float cnj[8];
#pragma unroll
        for (int j = 0; j < 8; j++) cnj[j] = cnorm[ct * BN + tx + 16 * j];

        float acc[8][8];
#pragma unroll
        for (int i = 0; i < 8; i++)
#pragma unroll
            for (int j = 0; j < 8; j++) acc[i][j] = 0.0f;

        for (int dc = 0; dc < D; dc += 32) {
            __syncthreads();
#pragma unroll
            for (int s = 0; s < 4; s++) {
                int q = tid + 256 * s;
                int row = q >> 3, c4 = q & 7;
                As[row * ROWF4 + c4] = *(const float4*)&X[(size_t)(pbase + row) * D + dc + c4 * 4];
                Bs[row * ROWF4 + c4] = *(const float4*)&C[(size_t)(ct * BN + row) * D + dc + c4 * 4];
            }
            __syncthreads();
#pragma unroll
            for (int d4 = 0; d4 < 8; d4++) {
                float4 av[8], bv[8];
#pragma unroll
                for (int i = 0; i < 8; i++) av[i] = As[(ty + 16 * i) * ROWF4 + d4];
#pragma unroll
                for (int j = 0; j < 8; j++) bv[j] = Bs[(tx + 16 * j) * ROWF4 + d4];
#pragma unroll
                for (int i = 0; i < 8; i++)
#pragma unroll
                    for (int j = 0; j < 8; j++) {
                        float a = acc[i][j];
                        a = __builtin_fmaf(av[i].x, bv[j].x, a);
                        a = __builtin_fmaf(av[i].y, bv[j].y, a);
                        a = __builtin_fmaf(av[i].z, bv[j].z, a);
                        a = __builtin_fmaf(av[i].w, bv[j].w, a);
                        acc[i][j] = a;
                    }
            }
        }

        // epilogue: s = (2*dot - xn) - cn; running top-2 (ascending c order)
#pragma unroll
        for (int i = 0; i < 8; i++)
#pragma unroll
            for (int j = 0; j < 8; j++) {
                int c = ct * BN + tx + 16 * j;
                float s2 = __fsub_rn(__fsub_rn(__fadd_rn(acc[i][j], acc[i][j]), xn[i]), cnj[j]);
                if (s2 > b1[i]) { b2[i] = b1[i]; b1[i] = s2; i1[i] = c; }
                else if (s2 > b2[i]) b2[i] = s2;
            }
    }

    // merge top-2 across the 16 tx lanes of each row group
#pragma unroll
    for (int i = 0; i < 8; i++) {
#pragma unroll
        for (int m = 1; m < 16; m <<= 1) {
            float ob1 = __shfl_xor(b1[i], m, 64);
            int   oi  = __shfl_xor(i1[i], m, 64);
            float ob2 = __shfl_xor(b2[i], m, 64);
            if (ob1 > b1[i])      { b2[i] = fmaxf(b1[i], ob2); b1[i] = ob1; i1[i] = oi; }
            else if (ob1 < b1[i]) { b2[i] = fmaxf(b2[i], ob1); }
            else                  { b2[i] = b1[i]; i1[i] = (oi < i1[i]) ? oi : i1[i]; }
        }
    }

    if (tx == 0) {
#pragma unroll
        for (int i = 0; i < 8; i++) {
            int p = pbase + ty + 16 * i;
            labels[p] = i1[i];
            if (b1[i] - b2[i] < TAU) {
                int idx = atomicAdd(counter, 1);
                list[idx] = p;
            }
        }
    }
}

// ---------------------------------------------------------------------------
// f64 recheck of flagged points: exact argmax over all 2048 clusters.
// CT64 is [d][k] so lanes read consecutive clusters (coalesced).
// ---------------------------------------------------------------------------
__global__ void recheck_kernel(const float* __restrict__ X,
                               const double* __restrict__ CT64,
                               const double* __restrict__ xn64,
                               const double* __restrict__ cn64,
                               const int* __restrict__ list,
                               const int* __restrict__ counter,
                               int* __restrict__ labels) {
    __shared__ float xrow[D];
    __shared__ double rb[4];
    __shared__ int ri[4];
    int cnt = *counter;
    for (int ii = blockIdx.x; ii < cnt; ii += gridDim.x) {
        int p = list[ii];
        __syncthreads();
        if (threadIdx.x < D) xrow[threadIdx.x] = X[(size_t)p * D + threadIdx.x];
        __syncthreads();
        double best = -1.0e300;
        int bi = 0x7fffffff;
#pragma unroll
        for (int g = 0; g < 8; g++) {
            int c = threadIdx.x + 256 * g;
            double acc = 0.0;
#pragma unroll 16
            for (int d = 0; d < D; d++)
                acc = fma((double)xrow[d], CT64[(size_t)d * KC + c], acc);
            double s = 2.0 * acc - xn64[p] - cn64[c];
            if (s > best || (s == best && c < bi)) { best = s; bi = c; }
        }
#pragma unroll
        for (int m = 1; m < 64; m <<= 1) {
            double ob = __shfl_xor(best, m, 64);
            int oi = __shfl_xor(bi, m, 64);
            if (ob > best || (ob == best && oi < bi)) { best = ob; bi = oi; }
        }
        int w = threadIdx.x >> 6;
        if ((threadIdx.x & 63) == 0) { rb[w] = best; ri[w] = bi; }
        __syncthreads();
        if (threadIdx.x == 0) {
            double bb = rb[0]; int bbi = ri[0];
            for (int w2 = 1; w2 < 4; w2++)
                if (rb[w2] > bb || (rb[w2] == bb && ri[w2] < bbi)) { bb = rb[w2]; bbi = ri[w2]; }
            labels[p] = bbi;
        }
    }
}

// ---------------------------------------------------------------------------
// Deterministic f64 segment sums: wave per cluster, ballot-gather ascending.
// ---------------------------------------------------------------------------
__global__ void accum_kernel(const float* __restrict__ X,
                             const int* __restrict__ labels,
                             double* __restrict__ sums,
                             int* __restrict__ counts) {
    int k = blockIdx.x * 4 + (threadIdx.x >> 6);
    int lane = threadIdx.x & 63;
    double s0 = 0.0, s1 = 0.0;
    int cnt = 0;
    for (int base = 0; base < NP; base += 64) {
        int lab = labels[base + lane];
        unsigned long long m = __ballot(lab == k);
        cnt += __popcll(m);
        while (m) {
            int b = __ffsll(m) - 1;
            m &= m - 1;
            float2 v = *(const float2*)&X[(size_t)(base + b) * D + lane * 2];
            s0 += (double)v.x;
            s1 += (double)v.y;
        }
    }
    sums[(size_t)k * D + lane * 2]     = s0;
    sums[(size_t)k * D + lane * 2 + 1] = s1;
    if (lane == 0) counts[k] = cnt;
}

// ---------------------------------------------------------------------------
// update: C = count>0 ? sum/count : 0 (f64), mirror to f32 + transposed f64
// ---------------------------------------------------------------------------
__global__ void update_kernel(const double* __restrict__ sums,
                              const int* __restrict__ counts,
                              double* __restrict__ C64, float* __restrict__ C32,
                              double* __restrict__ CT64, float* __restrict__ outC) {
    int t = blockIdx.x * 256 + threadIdx.x;       // 262144
    int k = t >> 7;
    int n = counts[k];
    double v = (n > 0) ? sums[t] / (double)n : 0.0;
    C64[t] = v;
    C32[t] = (float)v;
    CT64[(size_t)(t & 127) * KC + k] = v;
    if (outC) outC[t] = (float)v;
}

__global__ void lab2f_kernel(const int* __restrict__ labels, float* __restrict__ out) {
    int t = blockIdx.x * 256 + threadIdx.x;
    out[t] = (float)labels[t];
}

extern "C" void kernel_launch(void* const* d_in, const int* in_sizes, int n_in,
                              void* d_out, int out_size, void* d_ws, size_t ws_size,
                              hipStream_t stream) {
    const float* X = (const float*)d_in[0];
    const float* initC = (const float*)d_in[1];
    float* out = (float*)d_out;

    char* w = (char*)d_ws;
    double* C64    = (double*)(w);                     // 2 MB
    double* S64    = (double*)(w + (2u << 20));        // 2 MB
    double* CT64   = (double*)(w + (4u << 20));        // 2 MB
    double* xn64   = (double*)(w + (6u << 20));        // 1 MB
    double* cn64   = (double*)(w + (7u << 20));        // 16 KB
    float*  C32    = (float*) (w + (7u << 20) + (64u << 10));   // 1 MB
    float*  xn32   = (float*) (w + (8u << 20) + (64u << 10));   // 512 KB
    float*  cn32   = (float*) (w + (8u << 20) + (576u << 10));  // 8 KB
    int*    labels = (int*)   (w + (8u << 20) + (640u << 10));  // 512 KB
    int*    list   = (int*)   (w + (9u << 20) + (128u << 10));  // 512 KB
    int*    counts = (int*)   (w + (9u << 20) + (640u << 10));  // 8 KB
    int*    counter= (int*)   (w + (9u << 20) + (656u << 10));  // 4 B

    init_kernel<<<(KC * D) / 256, 256, 0, stream>>>(initC, C64, C32, CT64);
    xnorm_kernel<<<NP / 4, 256, 0, stream>>>(X, xn64, xn32);

    for (int it = 0; it < ITERS; it++) {
        cnorm_kernel<<<KC / 4, 256, 0, stream>>>(C64, cn64, cn32, counter);
        assign_kernel<<<NP / BM, 256, 0, stream>>>(X, C32, xn32, cn32, labels, list, counter);
        recheck_kernel<<<1024, 256, 0, stream>>>(X, CT64, xn64, cn64, list, counter, labels);
        accum_kernel<<<KC / 4, 256, 0, stream>>>(X, labels, S64, counts);
        update_kernel<<<(KC * D) / 256, 256, 0, stream>>>(
            S64, counts, C64, C32, CT64, (it == ITERS - 1) ? out : nullptr);
    }
    lab2f_kernel<<<NP / 256, 256, 0, stream>>>(labels, out + (size_t)KC * D);
}

// Round 5
// 7886.642 us; speedup vs baseline: 1.1809x; 1.0503x over previous
//
#include <hip/hip_runtime.h>

#define NP 131072
#define D 128
#define KC 2048
#define ITERS 5
#define CHMAX 16

#define BM 128
#define BN 128
#define ROWF4 9        // LDS row stride in float4 (32 floats + pad)
#define TAU 0.008f     // f32 top-2 gap below which we recheck in f64

// ---------------------------------------------------------------------------
// init: C64/C32/CT64 from init centroids
// ---------------------------------------------------------------------------
__global__ void init_kernel(const float* __restrict__ initC,
                            double* __restrict__ C64, float* __restrict__ C32,
                            double* __restrict__ CT64) {
    int t = blockIdx.x * 256 + threadIdx.x;       // 262144
    float v = initC[t];
    C64[t] = (double)v;
    C32[t] = v;
    CT64[(size_t)(t & 127) * KC + (t >> 7)] = (double)v;
}

// ---------------------------------------------------------------------------
// wave-per-row norms, f64 accumulate (exact products), write f64 + f32
// ---------------------------------------------------------------------------
__global__ void xnorm_kernel(const float* __restrict__ A,
                             double* __restrict__ n64, float* __restrict__ n32) {
    int r = blockIdx.x * 4 + (threadIdx.x >> 6);
    int lane = threadIdx.x & 63;
    float2 v = *(const float2*)&A[(size_t)r * D + lane * 2];
    double s = (double)v.x * (double)v.x + (double)v.y * (double)v.y;
#pragma unroll
    for (int m = 1; m < 64; m <<= 1) s += __shfl_xor(s, m, 64);
    if (lane == 0) { n64[r] = s; n32[r] = (float)s; }
}

__global__ void cnorm_kernel(const double* __restrict__ C64,
                             double* __restrict__ n64, float* __restrict__ n32,
                             int* __restrict__ counter) {
    int r = blockIdx.x * 4 + (threadIdx.x >> 6);
    int lane = threadIdx.x & 63;
    double a = C64[(size_t)r * D + lane * 2];
    double b = C64[(size_t)r * D + lane * 2 + 1];
    double s = a * a + b * b;
#pragma unroll
    for (int m = 1; m < 64; m <<= 1) s += __shfl_xor(s, m, 64);
    if (lane == 0) { n64[r] = s; n32[r] = (float)s; }
    if (blockIdx.x == 0 && threadIdx.x == 0) *counter = 0;
}

// ---------------------------------------------------------------------------
// Fast f32 GEMM + top-2 argmax. 128x128 tile, 256 thr, 8x8 micro-tile.
// __launch_bounds__(256,1): R4 showed (256,2) still left the allocator at
// 128 VGPR with ~190 live -> 800 MB/dispatch scratch traffic. Cap 512 so it
// can take what it needs; ~190 VGPR still gives 2 waves/SIMD.
// Points with top-2 gap < TAU get appended to the recheck list.
// ---------------------------------------------------------------------------
__global__ __launch_bounds__(256, 1)
void assign_kernel(const float* __restrict__ X,
                   const float* __restrict__ C,
                   const float* __restrict__ xnorm,
                   const float* __restrict__ cnorm,
                   int* __restrict__ labels,
                   int* __restrict__ list,
                   int* __restrict__ counter) {
    __shared__ float4 As[BM * ROWF4];
    __shared__ float4 Bs[BN * ROWF4];

    const int tid = threadIdx.x;
    const int tx = tid & 15;        // cluster direction
    const int ty = tid >> 4;        // point direction
    const int pbase = blockIdx.x * BM;

    float xn[8];
#pragma unroll
    for (int i = 0; i < 8; i++) xn[i] = xnorm[pbase + ty + 16 * i];

    float b1[8], b2[8];
    int i1[8];
#pragma unroll
    for (int i = 0; i < 8; i++) { b1[i] = -INFINITY; b2[i] = -INFINITY; i1[i] = 0x7fffffff; }

    for (int ct = 0; ct < KC / BN; ct++) {
        float cnj[8];
#pragma unroll
        for (int j = 0; j < 8; j++) cnj[j] = cnorm[ct * BN + tx + 16 * j];

        float acc[8][8];
#pragma unroll
        for (int i = 0; i < 8; i++)
#pragma unroll
            for (int j = 0; j < 8; j++) acc[i][j] = 0.0f;

        for (int dc = 0; dc < D; dc += 32) {
            __syncthreads();
#pragma unroll
            for (int s = 0; s < 4; s++) {
                int q = tid + 256 * s;
                int row = q >> 3, c4 = q & 7;
                As[row * ROWF4 + c4] = *(const float4*)&X[(size_t)(pbase + row) * D + dc + c4 * 4];
                Bs[row * ROWF4 + c4] = *(const float4*)&C[(size_t)(ct * BN + row) * D + dc + c4 * 4];
            }
            __syncthreads();
#pragma unroll
            for (int d4 = 0; d4 < 8; d4++) {
                float4 av[8], bv[8];
#pragma unroll
                for (int i = 0; i < 8; i++) av[i] = As[(ty + 16 * i) * ROWF4 + d4];
#pragma unroll
                for (int j = 0; j < 8; j++) bv[j] = Bs[(tx + 16 * j) * ROWF4 + d4];
#pragma unroll
                for (int i = 0; i < 8; i++)
#pragma unroll
                    for (int j = 0; j < 8; j++) {
                        float a = acc[i][j];
                        a = __builtin_fmaf(av[i].x, bv[j].x, a);
                        a = __builtin_fmaf(av[i].y, bv[j].y, a);
                        a = __builtin_fmaf(av[i].z, bv[j].z, a);
                        a = __builtin_fmaf(av[i].w, bv[j].w, a);
                        acc[i][j] = a;
                    }
            }
        }

        // epilogue: s = (2*dot - xn) - cn; running top-2 (ascending c order)
#pragma unroll
        for (int i = 0; i < 8; i++)
#pragma unroll
            for (int j = 0; j < 8; j++) {
                int c = ct * BN + tx + 16 * j;
                float s2 = __fsub_rn(__fsub_rn(__fadd_rn(acc[i][j], acc[i][j]), xn[i]), cnj[j]);
                if (s2 > b1[i]) { b2[i] = b1[i]; b1[i] = s2; i1[i] = c; }
                else if (s2 > b2[i]) b2[i] = s2;
            }
    }

    // merge top-2 across the 16 tx lanes of each row group
#pragma unroll
    for (int i = 0; i < 8; i++) {
#pragma unroll
        for (int m = 1; m < 16; m <<= 1) {
            float ob1 = __shfl_xor(b1[i], m, 64);
            int   oi  = __shfl_xor(i1[i], m, 64);
            float ob2 = __shfl_xor(b2[i], m, 64);
            if (ob1 > b1[i])      { b2[i] = fmaxf(b1[i], ob2); b1[i] = ob1; i1[i] = oi; }
            else if (ob1 < b1[i]) { b2[i] = fmaxf(b2[i], ob1); }
            else                  { b2[i] = b1[i]; i1[i] = (oi < i1[i]) ? oi : i1[i]; }
        }
    }

    if (tx == 0) {
#pragma unroll
        for (int i = 0; i < 8; i++) {
            int p = pbase + ty + 16 * i;
            labels[p] = i1[i];
            if (b1[i] - b2[i] < TAU) {
                int idx = atomicAdd(counter, 1);
                list[idx] = p;
            }
        }
    }
}

// ---------------------------------------------------------------------------
// f64 recheck of flagged points: exact argmax over all 2048 clusters.
// CT64 is [d][k] so lanes read consecutive clusters (coalesced).
// ---------------------------------------------------------------------------
__global__ void recheck_kernel(const float* __restrict__ X,
                               const double* __restrict__ CT64,
                               const double* __restrict__ xn64,
                               const double* __restrict__ cn64,
                               const int* __restrict__ list,
                               const int* __restrict__ counter,
                               int* __restrict__ labels) {
    __shared__ float xrow[D];
    __shared__ double rb[4];
    __shared__ int ri[4];
    int cnt = *counter;
    for (int ii = blockIdx.x; ii < cnt; ii += gridDim.x) {
        int p = list[ii];
        __syncthreads();
        if (threadIdx.x < D) xrow[threadIdx.x] = X[(size_t)p * D + threadIdx.x];
        __syncthreads();
        double best = -1.0e300;
        int bi = 0x7fffffff;
#pragma unroll
        for (int g = 0; g < 8; g++) {
            int c = threadIdx.x + 256 * g;
            double acc = 0.0;
#pragma unroll 16
            for (int d = 0; d < D; d++)
                acc = fma((double)xrow[d], CT64[(size_t)d * KC + c], acc);
            double s = 2.0 * acc - xn64[p] - cn64[c];
            if (s > best || (s == best && c < bi)) { best = s; bi = c; }
        }
#pragma unroll
        for (int m = 1; m < 64; m <<= 1) {
            double ob = __shfl_xor(best, m, 64);
            int oi = __shfl_xor(bi, m, 64);
            if (ob > best || (ob == best && oi < bi)) { best = ob; bi = oi; }
        }
        int w = threadIdx.x >> 6;
        if ((threadIdx.x & 63) == 0) { rb[w] = best; ri[w] = bi; }
        __syncthreads();
        if (threadIdx.x == 0) {
            double bb = rb[0]; int bbi = ri[0];
            for (int w2 = 1; w2 < 4; w2++)
                if (rb[w2] > bb || (rb[w2] == bb && ri[w2] < bbi)) { bb = rb[w2]; bbi = ri[w2]; }
            labels[p] = bbi;
        }
    }
}

// ---------------------------------------------------------------------------
// Deterministic chunked f64 segment sums. Chunk ch of CH scans points
// [ch*npc, (ch+1)*npc) in ascending ballot order -> partial[ch][k][:].
// Fixed chunk boundaries + fixed combine order in update = bit-stable.
// ---------------------------------------------------------------------------
__global__ void accum_part_kernel(const float* __restrict__ X,
                                  const int* __restrict__ labels,
                                  double* __restrict__ partial,
                                  int* __restrict__ pcnt,
                                  int npc) {
    int k = blockIdx.x * 4 + (threadIdx.x >> 6);
    int ch = blockIdx.y;
    int lane = threadIdx.x & 63;
    int p0 = ch * npc;
    double s0 = 0.0, s1 = 0.0;
    int cnt = 0;
    for (int base = p0; base < p0 + npc; base += 64) {
        int lab = labels[base + lane];
        unsigned long long m = __ballot(lab == k);
        cnt += __popcll(m);
        while (m) {
            int b = __ffsll(m) - 1;
            m &= m - 1;
            float2 v = *(const float2*)&X[(size_t)(base + b) * D + lane * 2];
            s0 += (double)v.x;
            s1 += (double)v.y;
        }
    }
    size_t o = ((size_t)ch * KC + k) * D + lane * 2;
    partial[o]     = s0;
    partial[o + 1] = s1;
    if (lane == 0) pcnt[ch * KC + k] = cnt;
}

// ---------------------------------------------------------------------------
// update: combine partials (ascending chunk order), divide, mirror everywhere
// ---------------------------------------------------------------------------
__global__ void update_kernel(const double* __restrict__ partial,
                              const int* __restrict__ pcnt, int CH,
                              double* __restrict__ C64, float* __restrict__ C32,
                              double* __restrict__ CT64, float* __restrict__ outC) {
    int t = blockIdx.x * 256 + threadIdx.x;       // 262144
    int k = t >> 7;
    double s = 0.0;
    for (int ch = 0; ch < CH; ch++) s += partial[(size_t)ch * (KC * D) + t];
    int n = 0;
    for (int ch = 0; ch < CH; ch++) n += pcnt[ch * KC + k];
    double v = (n > 0) ? s / (double)n : 0.0;
    C64[t] = v;
    C32[t] = (float)v;
    CT64[(size_t)(t & 127) * KC + k] = v;
    if (outC) outC[t] = (float)v;
}

__global__ void lab2f_kernel(const int* __restrict__ labels, float* __restrict__ out) {
    int t = blockIdx.x * 256 + threadIdx.x;
    out[t] = (float)labels[t];
}

extern "C" void kernel_launch(void* const* d_in, const int* in_sizes, int n_in,
                              void* d_out, int out_size, void* d_ws, size_t ws_size,
                              hipStream_t stream) {
    const float* X = (const float*)d_in[0];
    const float* initC = (const float*)d_in[1];
    float* out = (float*)d_out;

    char* w = (char*)d_ws;
    const size_t MB = 1u << 20;
    double* C64    = (double*)(w);                         // 2 MB
    double* CT64   = (double*)(w + 2 * MB);                // 2 MB
    double* xn64   = (double*)(w + 4 * MB);                // 1 MB
    float*  C32    = (float*) (w + 5 * MB);                // 1 MB
    float*  xn32   = (float*) (w + 6 * MB);                // 512 KB
    int*    labels = (int*)   (w + 6 * MB + 512 * 1024);   // 512 KB
    int*    list   = (int*)   (w + 7 * MB);                // 512 KB
    double* cn64   = (double*)(w + 7 * MB + 512 * 1024);   // 16 KB
    float*  cn32   = (float*) (w + 7 * MB + 528 * 1024);   // 8 KB
    int*    pcnt   = (int*)   (w + 7 * MB + 536 * 1024);   // 128 KB (CHMAX*KC*4)
    int*    counter= (int*)   (w + 7 * MB + 664 * 1024);   // 4 B
    size_t  poff   = 7 * MB + 672 * 1024;
    double* partial= (double*)(w + poff);                  // CH * 2 MB

    // Largest power-of-2 chunk count (<=CHMAX) whose partials fit in ws.
    int CH = 1;
    while (CH < CHMAX && poff + (size_t)(CH * 2) * KC * D * sizeof(double) <= ws_size)
        CH *= 2;

    init_kernel<<<(KC * D) / 256, 256, 0, stream>>>(initC, C64, C32, CT64);
    xnorm_kernel<<<NP / 4, 256, 0, stream>>>(X, xn64, xn32);

    for (int it = 0; it < ITERS; it++) {
        cnorm_kernel<<<KC / 4, 256, 0, stream>>>(C64, cn64, cn32, counter);
        assign_kernel<<<NP / BM, 256, 0, stream>>>(X, C32, xn32, cn32, labels, list, counter);
        recheck_kernel<<<1024, 256, 0, stream>>>(X, CT64, xn64, cn64, list, counter, labels);
        accum_part_kernel<<<dim3(KC / 4, CH), 256, 0, stream>>>(X, labels, partial, pcnt, NP / CH);
        update_kernel<<<(KC * D) / 256, 256, 0, stream>>>(
            partial, pcnt, CH, C64, C32, CT64, (it == ITERS - 1) ? out : nullptr);
    }
    lab2f_kernel<<<NP / 256, 256, 0, stream>>>(labels, out + (size_t)KC * D);
}

// Round 7
// 2838.110 us; speedup vs baseline: 3.2817x; 2.7788x over previous
//
#include <hip/hip_runtime.h>
#include <hip/hip_bf16.h>

#define NP 131072
#define D 128
#define KC 2048
#define ITERS 5

#define TAU 0.03f      // bf16x3 top-2 gap below which we recheck in f64

typedef short bf16x8 __attribute__((ext_vector_type(8)));
typedef float f32x4 __attribute__((ext_vector_type(4)));

__device__ inline unsigned short f2bf(float x) {
    __hip_bfloat16 b = __float2bfloat16(x);
    return *reinterpret_cast<unsigned short*>(&b);
}
__device__ inline float bf2f(unsigned short u) {
    union { unsigned int i; float f; } c; c.i = ((unsigned int)u) << 16; return c.f;
}

// ---------------------------------------------------------------------------
// init: C64/C32/CT64 from init centroids
// ---------------------------------------------------------------------------
__global__ void init_kernel(const float* __restrict__ initC,
                            double* __restrict__ C64, float* __restrict__ C32,
                            double* __restrict__ CT64) {
    int t = blockIdx.x * 256 + threadIdx.x;       // 262144
    float v = initC[t];
    C64[t] = (double)v;
    C32[t] = v;
    CT64[(size_t)(t & 127) * KC + (t >> 7)] = (double)v;
}

__global__ void xnorm_kernel(const float* __restrict__ A,
                             double* __restrict__ n64, float* __restrict__ n32) {
    int r = blockIdx.x * 4 + (threadIdx.x >> 6);
    int lane = threadIdx.x & 63;
    float2 v = *(const float2*)&A[(size_t)r * D + lane * 2];
    double s = (double)v.x * (double)v.x + (double)v.y * (double)v.y;
#pragma unroll
    for (int m = 1; m < 64; m <<= 1) s += __shfl_xor(s, m, 64);
    if (lane == 0) { n64[r] = s; n32[r] = (float)s; }
}

__global__ void cnorm_kernel(const double* __restrict__ C64,
                             double* __restrict__ n64, float* __restrict__ n32,
                             int* __restrict__ counter) {
    int r = blockIdx.x * 4 + (threadIdx.x >> 6);
    int lane = threadIdx.x & 63;
    double a = C64[(size_t)r * D + lane * 2];
    double b = C64[(size_t)r * D + lane * 2 + 1];
    double s = a * a + b * b;
#pragma unroll
    for (int m = 1; m < 64; m <<= 1) s += __shfl_xor(s, m, 64);
    if (lane == 0) { n64[r] = s; n32[r] = (float)s; }
    if (blockIdx.x == 0 && threadIdx.x == 0) *counter = 0;
}

// ---------------------------------------------------------------------------
// bf16x3 MFMA assign. Block = 128 points x 128 clusters/chunk, 4 waves
// (each wave: 64 rows x 64 cols of the chunk). A-tile (h+l, K=128, 64 KB)
// staged once, XOR-swizzled. B-chunk (128 cols x 32 k, h+l, 16 KB) per ks.
// dot ~ xh*ch + xh*cl + xl*ch (3 MFMA). Per-wave top-2 merged across the
// two wcol-waves via LDS (aliased onto Bh) -> labels + TAU recheck list.
// ---------------------------------------------------------------------------
__global__ __launch_bounds__(256, 2)
void assign_kernel(const float* __restrict__ X,
                   const float* __restrict__ C32,
                   const float* __restrict__ xnorm,
                   const float* __restrict__ cnorm,
                   int* __restrict__ labels,
                   int* __restrict__ list,
                   int* __restrict__ counter) {
    __shared__ __align__(16) unsigned short Ah[128 * 128];
    __shared__ __align__(16) unsigned short Al[128 * 128];
    __shared__ __align__(16) unsigned short Bh[128 * 32];
    __shared__ __align__(16) unsigned short Bl[128 * 32];

    const int tid = threadIdx.x;
    const int lane = tid & 63;
    const int wid = tid >> 6;
    const int wrow = wid >> 1;          // 0..1
    const int wcol = wid & 1;           // 0..1
    const int t15 = lane & 15;
    const int q = lane >> 4;            // 0..3
    const int pbase = blockIdx.x * 128;

    // ---- stage A tile (128 rows x 128 k), split to bf16 h/l, swizzled ----
#pragma unroll 4
    for (int i = 0; i < 16; i++) {
        int f = i * 256 + tid;          // float4-slot over 128 rows x 32 slots
        int row = f >> 5, c4 = f & 31;
        float4 v = *(const float4*)&X[(size_t)(pbase + row) * D + c4 * 4];
        unsigned short h0 = f2bf(v.x), h1 = f2bf(v.y), h2 = f2bf(v.z), h3 = f2bf(v.w);
        unsigned short l0 = f2bf(v.x - bf2f(h0)), l1 = f2bf(v.y - bf2f(h1));
        unsigned short l2 = f2bf(v.z - bf2f(h2)), l3 = f2bf(v.w - bf2f(h3));
        uint2 ph = { (unsigned)h0 | ((unsigned)h1 << 16), (unsigned)h2 | ((unsigned)h3 << 16) };
        uint2 pl = { (unsigned)l0 | ((unsigned)l1 << 16), (unsigned)l2 | ((unsigned)l3 << 16) };
        int ad = (row * 256 + c4 * 8) ^ ((row & 7) << 4);
        *(uint2*)((char*)Ah + ad) = ph;
        *(uint2*)((char*)Al + ad) = pl;
    }

    // xnorm for my 16 row-slots
    float xnr[16];
#pragma unroll
    for (int rt = 0; rt < 4; rt++)
#pragma unroll
        for (int rg = 0; rg < 4; rg++)
            xnr[rt * 4 + rg] = xnorm[pbase + wrow * 64 + rt * 16 + q * 4 + rg];

    float b1[16], b2[16];
    int i1[16];
#pragma unroll
    for (int s = 0; s < 16; s++) { b1[s] = -INFINITY; b2[s] = -INFINITY; i1[s] = 0x7fffffff; }

    for (int ct = 0; ct < KC / 128; ct++) {
        const int ctbase = ct * 128;
        f32x4 acc[4][4];
#pragma unroll
        for (int rt = 0; rt < 4; rt++)
#pragma unroll
            for (int cj = 0; cj < 4; cj++) acc[rt][cj] = (f32x4){0.f, 0.f, 0.f, 0.f};

        for (int ks = 0; ks < 4; ks++) {
            __syncthreads();
            // stage B chunk: 128 cols x 32 k = 1024 float4-slots (4 x 256)
#pragma unroll
            for (int i = 0; i < 4; i++) {
                int f = i * 256 + tid;
                int col = f >> 3, c4 = f & 7;
                float4 v = *(const float4*)&C32[(size_t)(ctbase + col) * D + ks * 32 + c4 * 4];
                unsigned short h0 = f2bf(v.x), h1 = f2bf(v.y), h2 = f2bf(v.z), h3 = f2bf(v.w);
                unsigned short l0 = f2bf(v.x - bf2f(h0)), l1 = f2bf(v.y - bf2f(h1));
                unsigned short l2 = f2bf(v.z - bf2f(h2)), l3 = f2bf(v.w - bf2f(h3));
                uint2 ph = { (unsigned)h0 | ((unsigned)h1 << 16), (unsigned)h2 | ((unsigned)h3 << 16) };
                uint2 pl = { (unsigned)l0 | ((unsigned)l1 << 16), (unsigned)l2 | ((unsigned)l3 << 16) };
                int ad = (col * 64 + c4 * 8) ^ ((col & 7) << 4);
                *(uint2*)((char*)Bh + ad) = ph;
                *(uint2*)((char*)Bl + ad) = pl;
            }
            __syncthreads();

            // a-frags for my 4 row-tiles
            bf16x8 ah[4], al[4];
#pragma unroll
            for (int rt = 0; rt < 4; rt++) {
                int row = wrow * 64 + rt * 16 + t15;
                int ad = (row * 256 + ks * 64 + q * 16) ^ ((row & 7) << 4);
                ah[rt] = *(const bf16x8*)((const char*)Ah + ad);
                al[rt] = *(const bf16x8*)((const char*)Al + ad);
            }
            // stream b-frags per col-tile; 3 MFMA passes each
#pragma unroll
            for (int cj = 0; cj < 4; cj++) {
                int col = wcol * 64 + cj * 16 + t15;
                int bd = (col * 64 + q * 16) ^ ((col & 7) << 4);
                bf16x8 bh = *(const bf16x8*)((const char*)Bh + bd);
                bf16x8 bl = *(const bf16x8*)((const char*)Bl + bd);
#pragma unroll
                for (int rt = 0; rt < 4; rt++) {
                    acc[rt][cj] = __builtin_amdgcn_mfma_f32_16x16x32_bf16(ah[rt], bh, acc[rt][cj], 0, 0, 0);
                    acc[rt][cj] = __builtin_amdgcn_mfma_f32_16x16x32_bf16(ah[rt], bl, acc[rt][cj], 0, 0, 0);
                    acc[rt][cj] = __builtin_amdgcn_mfma_f32_16x16x32_bf16(al[rt], bh, acc[rt][cj], 0, 0, 0);
                }
            }
        }

        // epilogue: s = 2*dot - xn - cn, running top-2
#pragma unroll
        for (int cj = 0; cj < 4; cj++) {
            int col = ctbase + wcol * 64 + cj * 16 + t15;
            float cnv = cnorm[col];
#pragma unroll
            for (int rt = 0; rt < 4; rt++)
#pragma unroll
                for (int rg = 0; rg < 4; rg++) {
                    int s = rt * 4 + rg;
                    float sv = 2.0f * acc[rt][cj][rg] - xnr[s] - cnv;
                    if (sv > b1[s]) { b2[s] = b1[s]; b1[s] = sv; i1[s] = col; }
                    else if (sv > b2[s]) b2[s] = sv;
                }
        }
    }

    // merge top-2 across the 16 t15 lanes of each q-group (within wave)
#pragma unroll
    for (int s = 0; s < 16; s++) {
#pragma unroll
        for (int m = 1; m < 16; m <<= 1) {
            float ob1 = __shfl_xor(b1[s], m, 64);
            int   oi  = __shfl_xor(i1[s], m, 64);
            float ob2 = __shfl_xor(b2[s], m, 64);
            if (ob1 > b1[s])      { b2[s] = fmaxf(b1[s], ob2); b1[s] = ob1; i1[s] = oi; }
            else if (ob1 < b1[s]) { b2[s] = fmaxf(b2[s], ob1); }
            else                  { b2[s] = b1[s]; i1[s] = (oi < i1[s]) ? oi : i1[s]; }
        }
    }

    // cross-wave merge (wcol 0 vs 1) via LDS aliased onto Bh (3 KB needed)
    __syncthreads();                       // all LDS compute reads done
    float* mb1 = (float*)Bh;               // [2][128]
    float* mb2 = ((float*)Bh) + 256;       // [2][128]
    int*   mi1 = (int*)(((float*)Bh) + 512);   // [2][128]
    if (t15 == 0) {
#pragma unroll
        for (int rt = 0; rt < 4; rt++)
#pragma unroll
            for (int rg = 0; rg < 4; rg++) {
                int s = rt * 4 + rg;
                int row = wrow * 64 + rt * 16 + q * 4 + rg;
                mb1[wcol * 128 + row] = b1[s];
                mb2[wcol * 128 + row] = b2[s];
                mi1[wcol * 128 + row] = i1[s];
            }
    }
    __syncthreads();
    if (tid < 128) {
        float a1 = mb1[tid], a2 = mb2[tid];  int ai = mi1[tid];
        float c1 = mb1[128 + tid], c2 = mb2[128 + tid];  int ci = mi1[128 + tid];
        float best, second;  int bi;
        if (a1 > c1)      { best = a1; bi = ai; second = fmaxf(a2, c1); }
        else if (a1 < c1) { best = c1; bi = ci; second = fmaxf(c2, a1); }
        else              { best = a1; bi = (ai < ci) ? ai : ci; second = a1; }
        int p = pbase + tid;
        labels[p] = bi;
        if (best - second < TAU) {
            int idx = atomicAdd(counter, 1);
            list[idx] = p;
        }
    }
}

// ---------------------------------------------------------------------------
// f64 recheck of flagged points: exact argmax over all 2048 clusters.
// ---------------------------------------------------------------------------
__global__ void recheck_kernel(const float* __restrict__ X,
                               const double* __restrict__ CT64,
                               const double* __restrict__ xn64,
                               const double* __restrict__ cn64,
                               const int* __restrict__ list,
                               const int* __restrict__ counter,
                               int* __restrict__ labels) {
    __shared__ float xrow[D];
    __shared__ double rb[4];
    __shared__ int ri[4];
    int cnt = *counter;
    for (int ii = blockIdx.x; ii < cnt; ii += gridDim.x) {
        int p = list[ii];
        __syncthreads();
        if (threadIdx.x < D) xrow[threadIdx.x] = X[(size_t)p * D + threadIdx.x];
        __syncthreads();
        double best = -1.0e300;
        int bi = 0x7fffffff;
#pragma unroll
        for (int g = 0; g < 8; g++) {
            int c = threadIdx.x + 256 * g;
            double acc = 0.0;
#pragma unroll 16
            for (int d = 0; d < D; d++)
                acc = fma((double)xrow[d], CT64[(size_t)d * KC + c], acc);
            double s = 2.0 * acc - xn64[p] - cn64[c];
            if (s > best || (s == best && c < bi)) { best = s; bi = c; }
        }
#pragma unroll
        for (int m = 1; m < 64; m <<= 1) {
            double ob = __shfl_xor(best, m, 64);
            int oi = __shfl_xor(bi, m, 64);
            if (ob > best || (ob == best && oi < bi)) { best = ob; bi = oi; }
        }
        int w = threadIdx.x >> 6;
        if ((threadIdx.x & 63) == 0) { rb[w] = best; ri[w] = bi; }
        __syncthreads();
        if (threadIdx.x == 0) {
            double bb = rb[0]; int bbi = ri[0];
            for (int w2 = 1; w2 < 4; w2++)
                if (rb[w2] > bb || (rb[w2] == bb && ri[w2] < bbi)) { bb = rb[w2]; bbi = ri[w2]; }
            labels[p] = bbi;
        }
    }
}

// ---------------------------------------------------------------------------
// Deterministic f64 segment sums: block per cluster; 4 waves scan fixed
// quarter-ranges with int4 label loads; LDS combine in fixed wave order.
// ---------------------------------------------------------------------------
__global__ void accum_kernel(const float* __restrict__ X,
                             const int* __restrict__ labels,
                             double* __restrict__ sums,
                             int* __restrict__ counts) {
    __shared__ double sred[4][D];
    __shared__ int cred[4];
    const int k = blockIdx.x;
    const int lane = threadIdx.x & 63;
    const int w = threadIdx.x >> 6;
    const int base0 = w * (NP / 4);
    double s0 = 0.0, s1 = 0.0;
    int cnt = 0;
    for (int it = 0; it < (NP / 4) / 256; it++) {
        int4 lab = *(const int4*)&labels[base0 + it * 256 + lane * 4];
#pragma unroll
        for (int j = 0; j < 4; j++) {
            int lv = (j == 0) ? lab.x : (j == 1) ? lab.y : (j == 2) ? lab.z : lab.w;
            unsigned long long m = __ballot(lv == k);
            cnt += __popcll(m);
            while (m) {
                int b = __ffsll(m) - 1;
                m &= m - 1;
                int p = base0 + it * 256 + b * 4 + j;
                float2 v = *(const float2*)&X[(size_t)p * D + lane * 2];
                s0 += (double)v.x;
                s1 += (double)v.y;
            }
        }
    }
    sred[w][lane * 2] = s0;
    sred[w][lane * 2 + 1] = s1;
    if (lane == 0) cred[w] = cnt;
    __syncthreads();
    if (threadIdx.x < D) {
        int d = threadIdx.x;
        double s = ((sred[0][d] + sred[1][d]) + sred[2][d]) + sred[3][d];
        sums[(size_t)k * D + d] = s;
    }
    if (threadIdx.x == 0)
        counts[k] = ((cred[0] + cred[1]) + cred[2]) + cred[3];
}

// ---------------------------------------------------------------------------
// update: C = count>0 ? sum/count : 0 (f64), mirror to f32 + transposed f64
// ---------------------------------------------------------------------------
__global__ void update_kernel(const double* __restrict__ sums,
                              const int* __restrict__ counts,
                              double* __restrict__ C64, float* __restrict__ C32,
                              double* __restrict__ CT64, float* __restrict__ outC) {
    int t = blockIdx.x * 256 + threadIdx.x;       // 262144
    int k = t >> 7;
    int n = counts[k];
    double v = (n > 0) ? sums[t] / (double)n : 0.0;
    C64[t] = v;
    C32[t] = (float)v;
    CT64[(size_t)(t & 127) * KC + k] = v;
    if (outC) outC[t] = (float)v;
}

__global__ void lab2f_kernel(const int* __restrict__ labels, float* __restrict__ out) {
    int t = blockIdx.x * 256 + threadIdx.x;
    out[t] = (float)labels[t];
}

extern "C" void kernel_launch(void* const* d_in, const int* in_sizes, int n_in,
                              void* d_out, int out_size, void* d_ws, size_t ws_size,
                              hipStream_t stream) {
    const float* X = (const float*)d_in[0];
    const float* initC = (const float*)d_in[1];
    float* out = (float*)d_out;

    char* w = (char*)d_ws;
    const size_t MB = 1u << 20;
    double* C64    = (double*)(w);                         // 2 MB
    double* S64    = (double*)(w + 2 * MB);                // 2 MB
    double* CT64   = (double*)(w + 4 * MB);                // 2 MB
    double* xn64   = (double*)(w + 6 * MB);                // 1 MB
    double* cn64   = (double*)(w + 7 * MB);                // 16 KB
    float*  C32    = (float*) (w + 7 * MB + 64 * 1024);    // 1 MB
    float*  xn32   = (float*) (w + 8 * MB + 64 * 1024);    // 512 KB
    float*  cn32   = (float*) (w + 8 * MB + 576 * 1024);   // 8 KB
    int*    labels = (int*)   (w + 8 * MB + 640 * 1024);   // 512 KB
    int*    list   = (int*)   (w + 9 * MB + 128 * 1024);   // 512 KB
    int*    counts = (int*)   (w + 9 * MB + 640 * 1024);   // 8 KB
    int*    counter= (int*)   (w + 9 * MB + 656 * 1024);   // 4 B

    init_kernel<<<(KC * D) / 256, 256, 0, stream>>>(initC, C64, C32, CT64);
    xnorm_kernel<<<NP / 4, 256, 0, stream>>>(X, xn64, xn32);

    for (int it = 0; it < ITERS; it++) {
        cnorm_kernel<<<KC / 4, 256, 0, stream>>>(C64, cn64, cn32, counter);
        assign_kernel<<<NP / 128, 256, 0, stream>>>(X, C32, xn32, cn32, labels, list, counter);
        recheck_kernel<<<1024, 256, 0, stream>>>(X, CT64, xn64, cn64, list, counter, labels);
        accum_kernel<<<KC, 256, 0, stream>>>(X, labels, S64, counts);
        update_kernel<<<(KC * D) / 256, 256, 0, stream>>>(
            S64, counts, C64, C32, CT64, (it == ITERS - 1) ? out : nullptr);
    }
    lab2f_kernel<<<NP / 256, 256, 0, stream>>>(labels, out + (size_t)KC * D);
}

// Round 8
// 2781.319 us; speedup vs baseline: 3.3487x; 1.0204x over previous
//
#include <hip/hip_runtime.h>
#include <hip/hip_bf16.h>

#define NP 131072
#define D 128
#define KC 2048
#define ITERS 5

#define TAU 0.03f      // bf16x3 top-2 gap below which we recheck in f64

typedef short bf16x8 __attribute__((ext_vector_type(8)));
typedef float f32x4 __attribute__((ext_vector_type(4)));

__device__ inline unsigned short f2bf(float x) {
    __hip_bfloat16 b = __float2bfloat16(x);
    return *reinterpret_cast<unsigned short*>(&b);
}
__device__ inline float bf2f(unsigned short u) {
    union { unsigned int i; float f; } c; c.i = ((unsigned int)u) << 16; return c.f;
}

// ---------------------------------------------------------------------------
// init: C64 / CT64 / packed bf16 split (Ch,Cl) from init centroids
// ---------------------------------------------------------------------------
__global__ void init_kernel(const float* __restrict__ initC,
                            double* __restrict__ C64, double* __restrict__ CT64,
                            unsigned short* __restrict__ Ch,
                            unsigned short* __restrict__ Cl) {
    int t = blockIdx.x * 256 + threadIdx.x;       // 262144
    float v = initC[t];
    C64[t] = (double)v;
    CT64[(size_t)(t & 127) * KC + (t >> 7)] = (double)v;
    unsigned short h = f2bf(v);
    Ch[t] = h;
    Cl[t] = f2bf(v - bf2f(h));
}

// wave-per-row point norms (f64 accumulate), stored f32 for the fast path
__global__ void xnorm_kernel(const float* __restrict__ A, float* __restrict__ n32) {
    int r = blockIdx.x * 4 + (threadIdx.x >> 6);
    int lane = threadIdx.x & 63;
    float2 v = *(const float2*)&A[(size_t)r * D + lane * 2];
    double s = (double)v.x * (double)v.x + (double)v.y * (double)v.y;
#pragma unroll
    for (int m = 1; m < 64; m <<= 1) s += __shfl_xor(s, m, 64);
    if (lane == 0) n32[r] = (float)s;
}

__global__ void cnorm_kernel(const double* __restrict__ C64,
                             double* __restrict__ n64, float* __restrict__ n32,
                             int* __restrict__ counter) {
    int r = blockIdx.x * 4 + (threadIdx.x >> 6);
    int lane = threadIdx.x & 63;
    double a = C64[(size_t)r * D + lane * 2];
    double b = C64[(size_t)r * D + lane * 2 + 1];
    double s = a * a + b * b;
#pragma unroll
    for (int m = 1; m < 64; m <<= 1) s += __shfl_xor(s, m, 64);
    if (lane == 0) { n64[r] = s; n32[r] = (float)s; }
    if (blockIdx.x == 0 && threadIdx.x == 0) *counter = 0;
}

// ---------------------------------------------------------------------------
// bf16x3 MFMA assign. Block = 128 points x 128 clusters/chunk, 4 waves.
// A-tile (h+l, K=128, 64 KB) staged+split once per block, XOR-swizzled.
// B-chunk (128 cols x 32 k) loaded PRE-SPLIT from Ch/Cl (uint2) per ks —
// no per-block f32->bf16 conversion (R7: that conversion was 64% VALUBusy).
// dot ~ xh*ch + xh*cl + xl*ch (3 MFMA). Cross-wave top-2 merge via LDS.
// ---------------------------------------------------------------------------
__global__ __launch_bounds__(256, 2)
void assign_kernel(const float* __restrict__ X,
                   const unsigned short* __restrict__ Ch,
                   const unsigned short* __restrict__ Cl,
                   const float* __restrict__ xnorm,
                   const float* __restrict__ cnorm,
                   int* __restrict__ labels,
                   int* __restrict__ list,
                   int* __restrict__ counter) {
    __shared__ __align__(16) unsigned short Ah[128 * 128];
    __shared__ __align__(16) unsigned short Al[128 * 128];
    __shared__ __align__(16) unsigned short Bh[128 * 32];
    __shared__ __align__(16) unsigned short Bl[128 * 32];

    const int tid = threadIdx.x;
    const int lane = tid & 63;
    const int wid = tid >> 6;
    const int wrow = wid >> 1;          // 0..1
    const int wcol = wid & 1;           // 0..1
    const int t15 = lane & 15;
    const int q = lane >> 4;            // 0..3
    const int pbase = blockIdx.x * 128;

    // ---- stage A tile (128 rows x 128 k), split to bf16 h/l, swizzled ----
#pragma unroll 4
    for (int i = 0; i < 16; i++) {
        int f = i * 256 + tid;          // float4-slot over 128 rows x 32 slots
        int row = f >> 5, c4 = f & 31;
        float4 v = *(const float4*)&X[(size_t)(pbase + row) * D + c4 * 4];
        unsigned short h0 = f2bf(v.x), h1 = f2bf(v.y), h2 = f2bf(v.z), h3 = f2bf(v.w);
        unsigned short l0 = f2bf(v.x - bf2f(h0)), l1 = f2bf(v.y - bf2f(h1));
        unsigned short l2 = f2bf(v.z - bf2f(h2)), l3 = f2bf(v.w - bf2f(h3));
        uint2 ph = { (unsigned)h0 | ((unsigned)h1 << 16), (unsigned)h2 | ((unsigned)h3 << 16) };
        uint2 pl = { (unsigned)l0 | ((unsigned)l1 << 16), (unsigned)l2 | ((unsigned)l3 << 16) };
        int ad = (row * 256 + c4 * 8) ^ ((row & 7) << 4);
        *(uint2*)((char*)Ah + ad) = ph;
        *(uint2*)((char*)Al + ad) = pl;
    }

    // xnorm for my 16 row-slots
    float xnr[16];
#pragma unroll
    for (int rt = 0; rt < 4; rt++)
#pragma unroll
        for (int rg = 0; rg < 4; rg++)
            xnr[rt * 4 + rg] = xnorm[pbase + wrow * 64 + rt * 16 + q * 4 + rg];

    float b1[16], b2[16];
    int i1[16];
#pragma unroll
    for (int s = 0; s < 16; s++) { b1[s] = -INFINITY; b2[s] = -INFINITY; i1[s] = 0x7fffffff; }

    for (int ct = 0; ct < KC / 128; ct++) {
        const int ctbase = ct * 128;
        f32x4 acc[4][4];
#pragma unroll
        for (int rt = 0; rt < 4; rt++)
#pragma unroll
            for (int cj = 0; cj < 4; cj++) acc[rt][cj] = (f32x4){0.f, 0.f, 0.f, 0.f};

        for (int ks = 0; ks < 4; ks++) {
            __syncthreads();
            // stage B chunk: 128 cols x 32 k = 1024 uint2-slots (4 x 256)
#pragma unroll
            for (int i = 0; i < 4; i++) {
                int f = i * 256 + tid;
                int col = f >> 3, c4 = f & 7;
                size_t go = (size_t)(ctbase + col) * D + ks * 32 + c4 * 4;
                uint2 ph = *(const uint2*)&Ch[go];
                uint2 pl = *(const uint2*)&Cl[go];
                int ad = (col * 64 + c4 * 8) ^ ((col & 7) << 4);
                *(uint2*)((char*)Bh + ad) = ph;
                *(uint2*)((char*)Bl + ad) = pl;
            }
            __syncthreads();

            // a-frags for my 4 row-tiles
            bf16x8 ah[4], al[4];
#pragma unroll
            for (int rt = 0; rt < 4; rt++) {
                int row = wrow * 64 + rt * 16 + t15;
                int ad = (row * 256 + ks * 64 + q * 16) ^ ((row & 7) << 4);
                ah[rt] = *(const bf16x8*)((const char*)Ah + ad);
                al[rt] = *(const bf16x8*)((const char*)Al + ad);
            }
            // stream b-frags per col-tile; 3 MFMA passes each
#pragma unroll
            for (int cj = 0; cj < 4; cj++) {
                int col = wcol * 64 + cj * 16 + t15;
                int bd = (col * 64 + q * 16) ^ ((col & 7) << 4);
                bf16x8 bh = *(const bf16x8*)((const char*)Bh + bd);
                bf16x8 bl = *(const bf16x8*)((const char*)Bl + bd);
#pragma unroll
                for (int rt = 0; rt < 4; rt++) {
                    acc[rt][cj] = __builtin_amdgcn_mfma_f32_16x16x32_bf16(ah[rt], bh, acc[rt][cj], 0, 0, 0);
                    acc[rt][cj] = __builtin_amdgcn_mfma_f32_16x16x32_bf16(ah[rt], bl, acc[rt][cj], 0, 0, 0);
                    acc[rt][cj] = __builtin_amdgcn_mfma_f32_16x16x32_bf16(al[rt], bh, acc[rt][cj], 0, 0, 0);
                }
            }
        }

        // epilogue: s = 2*dot - xn - cn, running top-2
#pragma unroll
        for (int cj = 0; cj < 4; cj++) {
            int col = ctbase + wcol * 64 + cj * 16 + t15;
            float cnv = cnorm[col];
#pragma unroll
            for (int rt = 0; rt < 4; rt++)
#pragma unroll
                for (int rg = 0; rg < 4; rg++) {
                    int s = rt * 4 + rg;
                    float sv = 2.0f * acc[rt][cj][rg] - xnr[s] - cnv;
                    if (sv > b1[s]) { b2[s] = b1[s]; b1[s] = sv; i1[s] = col; }
                    else if (sv > b2[s]) b2[s] = sv;
                }
        }
    }

    // merge top-2 across the 16 t15 lanes of each q-group (within wave)
#pragma unroll
    for (int s = 0; s < 16; s++) {
#pragma unroll
        for (int m = 1; m < 16; m <<= 1) {
            float ob1 = __shfl_xor(b1[s], m, 64);
            int   oi  = __shfl_xor(i1[s], m, 64);
            float ob2 = __shfl_xor(b2[s], m, 64);
            if (ob1 > b1[s])      { b2[s] = fmaxf(b1[s], ob2); b1[s] = ob1; i1[s] = oi; }
            else if (ob1 < b1[s]) { b2[s] = fmaxf(b2[s], ob1); }
            else                  { b2[s] = b1[s]; i1[s] = (oi < i1[s]) ? oi : i1[s]; }
        }
    }

    // cross-wave merge (wcol 0 vs 1) via LDS aliased onto Bh (3 KB needed)
    __syncthreads();                       // all LDS compute reads done
    float* mb1 = (float*)Bh;               // [2][128]
    float* mb2 = ((float*)Bh) + 256;       // [2][128]
    int*   mi1 = (int*)(((float*)Bh) + 512);   // [2][128]
    if (t15 == 0) {
#pragma unroll
        for (int rt = 0; rt < 4; rt++)
#pragma unroll
            for (int rg = 0; rg < 4; rg++) {
                int s = rt * 4 + rg;
                int row = wrow * 64 + rt * 16 + q * 4 + rg;
                mb1[wcol * 128 + row] = b1[s];
                mb2[wcol * 128 + row] = b2[s];
                mi1[wcol * 128 + row] = i1[s];
            }
    }
    __syncthreads();
    if (tid < 128) {
        float a1 = mb1[tid], a2 = mb2[tid];  int ai = mi1[tid];
        float c1 = mb1[128 + tid], c2 = mb2[128 + tid];  int ci = mi1[128 + tid];
        float best, second;  int bi;
        if (a1 > c1)      { best = a1; bi = ai; second = fmaxf(a2, c1); }
        else if (a1 < c1) { best = c1; bi = ci; second = fmaxf(c2, a1); }
        else              { best = a1; bi = (ai < ci) ? ai : ci; second = a1; }
        int p = pbase + tid;
        labels[p] = bi;
        if (best - second < TAU) {
            int idx = atomicAdd(counter, 1);
            list[idx] = p;
        }
    }
}

// ---------------------------------------------------------------------------
// f64 recheck of flagged points: exact argmax over all 2048 clusters.
// Point norm computed on the fly in f64 (deterministic, exact enough).
// ---------------------------------------------------------------------------
__global__ void recheck_kernel(const float* __restrict__ X,
                               const double* __restrict__ CT64,
                               const double* __restrict__ cn64,
                               const int* __restrict__ list,
                               const int* __restrict__ counter,
                               int* __restrict__ labels) {
    __shared__ float xrow[D];
    __shared__ double rb[4];
    __shared__ int ri[4];
    int cnt = *counter;
    for (int ii = blockIdx.x; ii < cnt; ii += gridDim.x) {
        int p = list[ii];
        __syncthreads();
        if (threadIdx.x < D) xrow[threadIdx.x] = X[(size_t)p * D + threadIdx.x];
        __syncthreads();
        double xn = 0.0;
#pragma unroll 16
        for (int d = 0; d < D; d++) {
            double xv = (double)xrow[d];
            xn = fma(xv, xv, xn);
        }
        double best = -1.0e300;
        int bi = 0x7fffffff;
#pragma unroll
        for (int g = 0; g < 8; g++) {
            int c = threadIdx.x + 256 * g;
            double acc = 0.0;
#pragma unroll 16
            for (int d = 0; d < D; d++)
                acc = fma((double)xrow[d], CT64[(size_t)d * KC + c], acc);
            double s = 2.0 * acc - xn - cn64[c];
            if (s > best || (s == best && c < bi)) { best = s; bi = c; }
        }
#pragma unroll
        for (int m = 1; m < 64; m <<= 1) {
            double ob = __shfl_xor(best, m, 64);
            int oi = __shfl_xor(bi, m, 64);
            if (ob > best || (ob == best && oi < bi)) { best = ob; bi = oi; }
        }
        int w = threadIdx.x >> 6;
        if ((threadIdx.x & 63) == 0) { rb[w] = best; ri[w] = bi; }
        __syncthreads();
        if (threadIdx.x == 0) {
            double bb = rb[0]; int bbi = ri[0];
            for (int w2 = 1; w2 < 4; w2++)
                if (rb[w2] > bb || (rb[w2] == bb && ri[w2] < bbi)) { bb = rb[w2]; bbi = ri[w2]; }
            labels[p] = bbi;
        }
    }
}

// ---------------------------------------------------------------------------
// Deterministic f64 segment sums: block per cluster; 4 waves scan fixed
// quarter-ranges with int4 label loads; LDS combine in fixed wave order.
// ---------------------------------------------------------------------------
__global__ void accum_kernel(const float* __restrict__ X,
                             const int* __restrict__ labels,
                             double* __restrict__ sums,
                             int* __restrict__ counts) {
    __shared__ double sred[4][D];
    __shared__ int cred[4];
    const int k = blockIdx.x;
    const int lane = threadIdx.x & 63;
    const int w = threadIdx.x >> 6;
    const int base0 = w * (NP / 4);
    double s0 = 0.0, s1 = 0.0;
    int cnt = 0;
    for (int it = 0; it < (NP / 4) / 256; it++) {
        int4 lab = *(const int4*)&labels[base0 + it * 256 + lane * 4];
#pragma unroll
        for (int j = 0; j < 4; j++) {
            int lv = (j == 0) ? lab.x : (j == 1) ? lab.y : (j == 2) ? lab.z : lab.w;
            unsigned long long m = __ballot(lv == k);
            cnt += __popcll(m);
            while (m) {
                int b = __ffsll(m) - 1;
                m &= m - 1;
                int p = base0 + it * 256 + b * 4 + j;
                float2 v = *(const float2*)&X[(size_t)p * D + lane * 2];
                s0 += (double)v.x;
                s1 += (double)v.y;
            }
        }
    }
    sred[w][lane * 2] = s0;
    sred[w][lane * 2 + 1] = s1;
    if (lane == 0) cred[w] = cnt;
    __syncthreads();
    if (threadIdx.x < D) {
        int d = threadIdx.x;
        double s = ((sred[0][d] + sred[1][d]) + sred[2][d]) + sred[3][d];
        sums[(size_t)k * D + d] = s;
    }
    if (threadIdx.x == 0)
        counts[k] = ((cred[0] + cred[1]) + cred[2]) + cred[3];
}

// ---------------------------------------------------------------------------
// update: C = count>0 ? sum/count : 0 (f64); mirror to CT64 + bf16 h/l split
// ---------------------------------------------------------------------------
__global__ void update_kernel(const double* __restrict__ sums,
                              const int* __restrict__ counts,
                              double* __restrict__ C64, double* __restrict__ CT64,
                              unsigned short* __restrict__ Ch,
                              unsigned short* __restrict__ Cl,
                              float* __restrict__ outC) {
    int t = blockIdx.x * 256 + threadIdx.x;       // 262144
    int k = t >> 7;
    int n = counts[k];
    double v = (n > 0) ? sums[t] / (double)n : 0.0;
    C64[t] = v;
    CT64[(size_t)(t & 127) * KC + k] = v;
    float vf = (float)v;
    unsigned short h = f2bf(vf);
    Ch[t] = h;
    Cl[t] = f2bf(vf - bf2f(h));
    if (outC) outC[t] = vf;
}

__global__ void lab2f_kernel(const int* __restrict__ labels, float* __restrict__ out) {
    int t = blockIdx.x * 256 + threadIdx.x;
    out[t] = (float)labels[t];
}

extern "C" void kernel_launch(void* const* d_in, const int* in_sizes, int n_in,
                              void* d_out, int out_size, void* d_ws, size_t ws_size,
                              hipStream_t stream) {
    const float* X = (const float*)d_in[0];
    const float* initC = (const float*)d_in[1];
    float* out = (float*)d_out;

    char* w = (char*)d_ws;
    const size_t MB = 1u << 20;
    double* C64    = (double*)(w);                          // 2 MB
    double* S64    = (double*)(w + 2 * MB);                 // 2 MB
    double* CT64   = (double*)(w + 4 * MB);                 // 2 MB
    unsigned short* Ch = (unsigned short*)(w + 6 * MB);     // 512 KB
    unsigned short* Cl = (unsigned short*)(w + 6 * MB + 512 * 1024); // 512 KB
    float*  xn32   = (float*) (w + 7 * MB);                 // 512 KB
    int*    labels = (int*)   (w + 7 * MB + 512 * 1024);    // 512 KB
    int*    list   = (int*)   (w + 8 * MB);                 // 512 KB
    double* cn64   = (double*)(w + 8 * MB + 512 * 1024);    // 16 KB
    float*  cn32   = (float*) (w + 8 * MB + 528 * 1024);    // 8 KB
    int*    counts = (int*)   (w + 8 * MB + 536 * 1024);    // 8 KB
    int*    counter= (int*)   (w + 8 * MB + 544 * 1024);    // 4 B

    init_kernel<<<(KC * D) / 256, 256, 0, stream>>>(initC, C64, CT64, Ch, Cl);
    xnorm_kernel<<<NP / 4, 256, 0, stream>>>(X, xn32);

    for (int it = 0; it < ITERS; it++) {
        cnorm_kernel<<<KC / 4, 256, 0, stream>>>(C64, cn64, cn32, counter);
        assign_kernel<<<NP / 128, 256, 0, stream>>>(X, Ch, Cl, xn32, cn32, labels, list, counter);
        recheck_kernel<<<1024, 256, 0, stream>>>(X, CT64, cn64, list, counter, labels);
        accum_kernel<<<KC, 256, 0, stream>>>(X, labels, S64, counts);
        update_kernel<<<(KC * D) / 256, 256, 0, stream>>>(
            S64, counts, C64, CT64, Ch, Cl, (it == ITERS - 1) ? out : nullptr);
    }
    lab2f_kernel<<<NP / 256, 256, 0, stream>>>(labels, out + (size_t)KC * D);
}